// Round 12
// baseline (158.543 us; speedup 1.0000x reference)
//
#include <hip/hip_runtime.h>

// Shapes: N=8, M=2048 -> 16384 rows; D=128, L=128.
// out0 h: (16384,128) fp32; out1 edge: (8,2048,2048) = e[row] broadcast.
//
// R11 post-mortem: split+swizzled confirmed (158.2us). Broadcast at fill BW
// (~22us = roofline for 136MB). Compute ~9us vs ~4.8us floor = L2 weight BW
// (1024 blocks x 160KB = 164MB). R12: 32-row tiles, grid 512 -> weight
// traffic halves to 82MB; stage decomposition identical to the validated
// R4/R5 4-wave 32-row structure; weights in R8 fragment order.

typedef short short8 __attribute__((ext_vector_type(8)));
typedef float floatx4 __attribute__((ext_vector_type(4)));

__device__ __forceinline__ short f2bf(float f) {
    union { float f; unsigned u; } v; v.f = f;
    unsigned r = v.u + 0x7fffu + ((v.u >> 16) & 1u);   // RNE
    return (short)(r >> 16);
}

// d_ws: shorts in MFMA-fragment order (unchanged from R8):
//   W1S at 0      (64KB): idx = ((ct*4+k)*64 + l)*8 + j, ct 0..15, k 0..3
//   W2S at 32768  (64KB): idx = ((ct*8+k)*64 + l)*8 + j, ct 0..7,  k 0..7
//   WES at 65536  (32KB): idx = ((ct*4+k)*64 + l)*8 + j, ct 0..7,  k 0..3
//   float es[16384] at byte 163840 (64KB)
// Requires ws_size >= 229376 bytes.
__global__ __launch_bounds__(256)
void prep_weights(const float* __restrict__ w1n, const float* __restrict__ w2n,
                  const float* __restrict__ w1e, short* __restrict__ ws)
{
    const int id = blockIdx.x * 256 + threadIdx.x;   // 0..81919
    const int j = id & 7;
    if (id < 32768) {
        const int g = id >> 3, l = g & 63, ctk = g >> 6;
        const int ct = ctk >> 2, k = ctk & 3;
        const int kg = k * 32 + (l >> 4) * 8 + j;
        ws[id] = f2bf(w1n[kg * 256 + ct * 16 + (l & 15)]);
    } else if (id < 65536) {
        const int g = (id - 32768) >> 3, l = g & 63, ctk = g >> 6;
        const int ct = ctk >> 3, k = ctk & 7;
        const int kg = k * 32 + (l >> 4) * 8 + j;
        ws[id] = f2bf(w2n[kg * 128 + ct * 16 + (l & 15)]);
    } else {
        const int g = (id - 65536) >> 3, l = g & 63, ctk = g >> 6;
        const int ct = ctk >> 2, k = ctk & 3;
        const int kg = k * 32 + (l >> 4) * 8 + j;
        ws[id] = f2bf(w1e[kg * 128 + ct * 16 + (l & 15)]
                      + w1e[(kg + 128) * 128 + ct * 16 + (l & 15)]);
    }
}

#define TPB 256
#define ROWS 32
#define H1_STRIDE 264    // 256 + 8 pad
#define HB_STRIDE 136    // 128 + 8 pad

// MFMA 16x16x32 bf16 lane mapping:
//   A: lane holds A[m = lane&15][k = (lane>>4)*8 + j], j=0..7
//   B: lane holds B[k = (lane>>4)*8 + j][n = lane&15]
//   C/D: reg r holds D[row = (lane>>4)*4 + r][col = lane&15]
__global__ __launch_bounds__(TPB, 2)
void node_compute(const float* __restrict__ x,
                  const float* __restrict__ b1n, const float* __restrict__ b2n,
                  const float* __restrict__ b1e,
                  const float* __restrict__ w2e, const float* __restrict__ b2e,
                  const short* __restrict__ wt,
                  float* __restrict__ h_out, float* __restrict__ e_ws)
{
    __shared__ short h1s[ROWS * H1_STRIDE];   // 16.9 KB
    __shared__ short hbs[ROWS * HB_STRIDE];   // 8.7 KB
    __shared__ float partial[4][ROWS];

    const int t = threadIdx.x;
    const int w = t >> 6;          // wave 0..3
    const int l = t & 63;
    const int l15 = l & 15;
    const int quad = l >> 4;
    const int row0 = blockIdx.x * ROWS;   // 512 blocks, one 32-row tile each

    const short* __restrict__ W2S = wt + 32768;
    const short* __restrict__ WES = wt + 65536;

    // ---- x -> A-fragments directly, both 16-row halves ----
    short8 a1[2][4];
#pragma unroll
    for (int rt = 0; rt < 2; ++rt)
#pragma unroll
        for (int k = 0; k < 4; ++k) {
            const float* p = x + (size_t)(row0 + rt * 16 + l15) * 128 + k * 32 + quad * 8;
            const float4 v0 = *(const float4*)p;
            const float4 v1 = *(const float4*)(p + 4);
            short8 a;
            a[0] = f2bf(v0.x); a[1] = f2bf(v0.y); a[2] = f2bf(v0.z); a[3] = f2bf(v0.w);
            a[4] = f2bf(v1.x); a[5] = f2bf(v1.y); a[6] = f2bf(v1.z); a[7] = f2bf(v1.w);
            a1[rt][k] = a;
        }

    // ---- stage 1: h1 = relu(X @ W1n + b1n), 4 col-tiles x 2 row-tiles/wave ----
#pragma unroll
    for (int ci = 0; ci < 4; ++ci) {
        const int ct = 4 * w + ci;
        const float b = b1n[ct * 16 + l15];
        floatx4 acc0 = (floatx4){b, b, b, b};
        floatx4 acc1v = (floatx4){b, b, b, b};
#pragma unroll
        for (int k = 0; k < 4; ++k) {
            const short8 bf = *(const short8*)(wt + ((ct * 4 + k) * 64 + l) * 8);
            acc0 = __builtin_amdgcn_mfma_f32_16x16x32_bf16(a1[0][k], bf, acc0, 0, 0, 0);
            acc1v = __builtin_amdgcn_mfma_f32_16x16x32_bf16(a1[1][k], bf, acc1v, 0, 0, 0);
        }
#pragma unroll
        for (int r = 0; r < 4; ++r) {
            h1s[(quad * 4 + r) * H1_STRIDE + ct * 16 + l15] = f2bf(fmaxf(acc0[r], 0.f));
            h1s[(16 + quad * 4 + r) * H1_STRIDE + ct * 16 + l15] = f2bf(fmaxf(acc1v[r], 0.f));
        }
    }
    __syncthreads();

    // ---- stage 2: h = h1 @ W2n + b2n, 2 col-tiles x 2 row-tiles/wave ----
    short8 a2[2][8];
#pragma unroll
    for (int rt = 0; rt < 2; ++rt)
#pragma unroll
        for (int k = 0; k < 8; ++k)
            a2[rt][k] = *(const short8*)&h1s[(rt * 16 + l15) * H1_STRIDE + k * 32 + quad * 8];

#pragma unroll
    for (int ci = 0; ci < 2; ++ci) {
        const int ct = 2 * w + ci;
        const float b = b2n[ct * 16 + l15];
        floatx4 acc0 = (floatx4){b, b, b, b};
        floatx4 acc1v = (floatx4){b, b, b, b};
#pragma unroll
        for (int k = 0; k < 8; ++k) {
            const short8 bf = *(const short8*)(W2S + ((ct * 8 + k) * 64 + l) * 8);
            acc0 = __builtin_amdgcn_mfma_f32_16x16x32_bf16(a2[0][k], bf, acc0, 0, 0, 0);
            acc1v = __builtin_amdgcn_mfma_f32_16x16x32_bf16(a2[1][k], bf, acc1v, 0, 0, 0);
        }
#pragma unroll
        for (int r = 0; r < 4; ++r) {
            const int rowa = quad * 4 + r, rowb = 16 + quad * 4 + r;
            h_out[(size_t)(row0 + rowa) * 128 + ct * 16 + l15] = acc0[r];
            h_out[(size_t)(row0 + rowb) * 128 + ct * 16 + l15] = acc1v[r];
            hbs[rowa * HB_STRIDE + ct * 16 + l15] = f2bf(acc0[r]);
            hbs[rowb * HB_STRIDE + ct * 16 + l15] = f2bf(acc1v[r]);
        }
    }
    __syncthreads();

    // ---- stage 3+4: t1 = relu(h @ WE + b1e); e = (t1 . w2e + b2e)/2048 ----
    short8 a3[2][4];
#pragma unroll
    for (int rt = 0; rt < 2; ++rt)
#pragma unroll
        for (int k = 0; k < 4; ++k)
            a3[rt][k] = *(const short8*)&hbs[(rt * 16 + l15) * HB_STRIDE + k * 32 + quad * 8];

    float p[2][4] = {{0.f, 0.f, 0.f, 0.f}, {0.f, 0.f, 0.f, 0.f}};
#pragma unroll
    for (int ci = 0; ci < 2; ++ci) {
        const int ct = 2 * w + ci;
        const float b = b1e[ct * 16 + l15];
        floatx4 acc0 = (floatx4){b, b, b, b};
        floatx4 acc1v = (floatx4){b, b, b, b};
#pragma unroll
        for (int k = 0; k < 4; ++k) {
            const short8 bf = *(const short8*)(WES + ((ct * 4 + k) * 64 + l) * 8);
            acc0 = __builtin_amdgcn_mfma_f32_16x16x32_bf16(a3[0][k], bf, acc0, 0, 0, 0);
            acc1v = __builtin_amdgcn_mfma_f32_16x16x32_bf16(a3[1][k], bf, acc1v, 0, 0, 0);
        }
        const float wv = w2e[ct * 16 + l15];
#pragma unroll
        for (int r = 0; r < 4; ++r) {
            p[0][r] += fmaxf(acc0[r], 0.f) * wv;
            p[1][r] += fmaxf(acc1v[r], 0.f) * wv;
        }
    }
#pragma unroll
    for (int off = 8; off >= 1; off >>= 1)
#pragma unroll
        for (int rt = 0; rt < 2; ++rt)
#pragma unroll
            for (int r = 0; r < 4; ++r)
                p[rt][r] += __shfl_xor(p[rt][r], off, 64);
    if (l15 == 0) {
#pragma unroll
        for (int rt = 0; rt < 2; ++rt)
#pragma unroll
            for (int r = 0; r < 4; ++r)
                partial[w][rt * 16 + quad * 4 + r] = p[rt][r];
    }
    __syncthreads();
    if (t < ROWS) {
        e_ws[row0 + t] = (partial[0][t] + partial[1][t] + partial[2][t]
                          + partial[3][t] + b2e[0]) * (1.0f / 2048.0f);
    }
}

// ---- pure streaming broadcast (unchanged from R11): 2048 blocks x 256 thr,
// 2 rows (16KB) per block, 4 coalesced float4 stores/thread. ----
__global__ __launch_bounds__(256)
void edge_broadcast(const float* __restrict__ es, float* __restrict__ edge_out)
{
    const int t = threadIdx.x;
    const int r0 = blockIdx.x * 2;
    const float v0 = es[r0];          // block-uniform -> scalar loads
    const float v1 = es[r0 + 1];
    floatx4* __restrict__ e4 = (floatx4*)(edge_out + (size_t)r0 * 2048);
    const floatx4 a = (floatx4){v0, v0, v0, v0};
    const floatx4 b = (floatx4){v1, v1, v1, v1};
    e4[t] = a;
    e4[t + 256] = a;
    e4[t + 512] = b;
    e4[t + 768] = b;
}

extern "C" void kernel_launch(void* const* d_in, const int* in_sizes, int n_in,
                              void* d_out, int out_size, void* d_ws, size_t ws_size,
                              hipStream_t stream) {
    const float* x   = (const float*)d_in[0];
    const float* w1n = (const float*)d_in[1];
    const float* b1n = (const float*)d_in[2];
    const float* w2n = (const float*)d_in[3];
    const float* b2n = (const float*)d_in[4];
    const float* w1e = (const float*)d_in[5];
    const float* b1e = (const float*)d_in[6];
    const float* w2e = (const float*)d_in[7];
    const float* b2e = (const float*)d_in[8];

    float* h_out    = (float*)d_out;                              // (8,2048,128)
    float* edge_out = (float*)d_out + (size_t)8 * 2048 * 128;     // (8,2048,2048)
    short* wt       = (short*)d_ws;                               // 160 KB swizzled bf16 weights
    float* e_ws     = (float*)((char*)d_ws + 163840);             // 64 KB e scalars

    prep_weights<<<dim3(320), dim3(256), 0, stream>>>(w1n, w2n, w1e, wt);
    node_compute<<<dim3(512), dim3(TPB), 0, stream>>>(
        x, b1n, b2n, b1e, w2e, b2e, wt, h_out, e_ws);
    edge_broadcast<<<dim3(2048), dim3(256), 0, stream>>>(e_ws, edge_out);
}